// Round 1
// baseline (253.940 us; speedup 1.0000x reference)
//
#include <hip/hip_runtime.h>
#include <stdint.h>

#define IN_F   4096
#define R_DIM  128
#define OUT_D  4096
#define BSZ    8
#define SEQ    2048
#define M1     (BSZ * SEQ)   /* 16384 */
#define SCALE  2.0f

typedef __attribute__((ext_vector_type(8))) short short8;
typedef __attribute__((ext_vector_type(4))) float f32x4;

static __device__ __forceinline__ unsigned short f32_to_bf16_rne(float f) {
    union { float f; uint32_t u; } v; v.f = f;
    uint32_t u = v.u;
    u += 0x7FFFu + ((u >> 16) & 1u);   // round-to-nearest-even
    return (unsigned short)(u >> 16);
}

static __device__ __forceinline__ void st_bf16x4(unsigned short* p, float4 v) {
    uint2 q;
    q.x = (uint32_t)f32_to_bf16_rne(v.x) | ((uint32_t)f32_to_bf16_rne(v.y) << 16);
    q.y = (uint32_t)f32_to_bf16_rne(v.z) | ((uint32_t)f32_to_bf16_rne(v.w) << 16);
    *(uint2*)p = q;
}

// ---------------- Pass 1: down[16384][128] (bf16) = x[16384][4096] @ W_down[128][4096]^T ----------------
#define BM1 64
#define BK1 64
#define PAD 8

__global__ __launch_bounds__(512) void k_down(const float* __restrict__ x,
                                              const float* __restrict__ Wd,
                                              unsigned short* __restrict__ down) {
    __shared__ unsigned short As[BM1][BK1 + PAD];      // 64 x 72 bf16
    __shared__ unsigned short Bs[R_DIM][BK1 + PAD];    // 128 x 72 bf16

    const int tid  = threadIdx.x;
    const int lane = tid & 63;
    const int w    = tid >> 6;   // 0..7
    const int wm   = w >> 2;     // 0..1  (rows: 2 waves x 32)
    const int wn   = w & 3;      // 0..3  (cols: 4 waves x 32)
    const int row0 = blockIdx.x * BM1;

    f32x4 acc[2][2];
#pragma unroll
    for (int m = 0; m < 2; ++m)
#pragma unroll
        for (int n = 0; n < 2; ++n)
#pragma unroll
            for (int j = 0; j < 4; ++j) acc[m][n][j] = 0.0f;

    // staging layout: 512 threads; thread -> (row = tid>>4 in 0..31, col4 = (tid&15)*4)
    const int arow = tid >> 4;
    const int acol = (tid & 15) << 2;

    float4 ra[2], rb[4];

    // prologue: load tile 0
    ra[0] = *(const float4*)(x + (size_t)(row0 + arow) * IN_F + acol);
    ra[1] = *(const float4*)(x + (size_t)(row0 + arow + 32) * IN_F + acol);
#pragma unroll
    for (int i = 0; i < 4; ++i)
        rb[i] = *(const float4*)(Wd + (size_t)(arow + 32 * i) * IN_F + acol);
    st_bf16x4(&As[arow][acol], ra[0]);
    st_bf16x4(&As[arow + 32][acol], ra[1]);
#pragma unroll
    for (int i = 0; i < 4; ++i) st_bf16x4(&Bs[arow + 32 * i][acol], rb[i]);
    __syncthreads();

    for (int k0 = BK1; k0 <= IN_F; k0 += BK1) {
        const bool more = (k0 < IN_F);
        if (more) {
            ra[0] = *(const float4*)(x + (size_t)(row0 + arow) * IN_F + k0 + acol);
            ra[1] = *(const float4*)(x + (size_t)(row0 + arow + 32) * IN_F + k0 + acol);
#pragma unroll
            for (int i = 0; i < 4; ++i)
                rb[i] = *(const float4*)(Wd + (size_t)(arow + 32 * i) * IN_F + k0 + acol);
        }
        // compute current tile
#pragma unroll
        for (int kk = 0; kk < BK1; kk += 32) {
            short8 af[2], bfv[2];
#pragma unroll
            for (int m = 0; m < 2; ++m)
                af[m] = *(const short8*)&As[wm * 32 + m * 16 + (lane & 15)][kk + (lane >> 4) * 8];
#pragma unroll
            for (int n = 0; n < 2; ++n)
                bfv[n] = *(const short8*)&Bs[wn * 32 + n * 16 + (lane & 15)][kk + (lane >> 4) * 8];
#pragma unroll
            for (int m = 0; m < 2; ++m)
#pragma unroll
                for (int n = 0; n < 2; ++n)
                    acc[m][n] = __builtin_amdgcn_mfma_f32_16x16x32_bf16(af[m], bfv[n], acc[m][n], 0, 0, 0);
        }
        __syncthreads();
        if (more) {
            st_bf16x4(&As[arow][acol], ra[0]);
            st_bf16x4(&As[arow + 32][acol], ra[1]);
#pragma unroll
            for (int i = 0; i < 4; ++i) st_bf16x4(&Bs[arow + 32 * i][acol], rb[i]);
            __syncthreads();
        }
    }

    // epilogue: write down tile as bf16
#pragma unroll
    for (int m = 0; m < 2; ++m)
#pragma unroll
        for (int n = 0; n < 2; ++n)
#pragma unroll
            for (int j = 0; j < 4; ++j) {
                int r = row0 + wm * 32 + m * 16 + ((lane >> 4) << 2) + j;
                int c = wn * 32 + n * 16 + (lane & 15);
                down[(size_t)r * R_DIM + c] = f32_to_bf16_rne(acc[m][n][j]);
            }
}

// ---------------- Pass 2: out[b][2048][4096] = down[b] @ graph_rep[b] * SCALE ----------------
#define BM2 64
#define BN2 128
#define KPAD (R_DIM + 8)   /* 136 */

__global__ __launch_bounds__(512) void k_out(const unsigned short* __restrict__ down,
                                             const float* __restrict__ g,
                                             float* __restrict__ out) {
    __shared__ unsigned short As[BM2][KPAD];   // 64 x 136 bf16
    __shared__ unsigned short Bs[BN2][KPAD];   // 128 x 136 bf16 (g transposed)

    const int tid  = threadIdx.x;
    const int lane = tid & 63;
    const int w    = tid >> 6;
    const int wm   = w >> 2;   // 0..1
    const int wn   = w & 3;    // 0..3
    const int blk  = blockIdx.x;
    const int o_t  = blk & 31;          // 32 o-tiles
    const int s_t  = (blk >> 5) & 31;   // 32 s-tiles
    const int b    = blk >> 10;         // 8 batches
    const int s0   = s_t * BM2;
    const int o0   = o_t * BN2;

    // stage A: down rows [b*SEQ + s0 .. +64), all 128 k, bf16 direct copy (uint4 = 8 elems)
    {
        const int rr = tid >> 4;          // 0..31
        const int c8 = (tid & 15) << 3;   // 0..120 step 8
        const uint4* src0 = (const uint4*)(down + ((size_t)(b * SEQ + s0 + rr) * R_DIM) + c8);
        const uint4* src1 = (const uint4*)(down + ((size_t)(b * SEQ + s0 + rr + 32) * R_DIM) + c8);
        *(uint4*)&As[rr][c8]      = *src0;
        *(uint4*)&As[rr + 32][c8] = *src1;
    }
    // stage B transposed: Bs[o][k] = bf16(g[b][k][o0+o])
    {
        const int kbase = tid >> 5;       // 0..15
        const int c4 = (tid & 31) << 2;   // 0..124 step 4
#pragma unroll
        for (int i = 0; i < 8; ++i) {
            int k = kbase + 16 * i;
            float4 v = *(const float4*)(g + ((size_t)b * R_DIM + k) * OUT_D + o0 + c4);
            Bs[c4 + 0][k] = f32_to_bf16_rne(v.x);
            Bs[c4 + 1][k] = f32_to_bf16_rne(v.y);
            Bs[c4 + 2][k] = f32_to_bf16_rne(v.z);
            Bs[c4 + 3][k] = f32_to_bf16_rne(v.w);
        }
    }
    __syncthreads();

    f32x4 acc[2][2];
#pragma unroll
    for (int m = 0; m < 2; ++m)
#pragma unroll
        for (int n = 0; n < 2; ++n)
#pragma unroll
            for (int j = 0; j < 4; ++j) acc[m][n][j] = 0.0f;

#pragma unroll
    for (int kk = 0; kk < R_DIM; kk += 32) {
        short8 af[2], bfv[2];
#pragma unroll
        for (int m = 0; m < 2; ++m)
            af[m] = *(const short8*)&As[wm * 32 + m * 16 + (lane & 15)][kk + (lane >> 4) * 8];
#pragma unroll
        for (int n = 0; n < 2; ++n)
            bfv[n] = *(const short8*)&Bs[wn * 32 + n * 16 + (lane & 15)][kk + (lane >> 4) * 8];
#pragma unroll
        for (int m = 0; m < 2; ++m)
#pragma unroll
            for (int n = 0; n < 2; ++n)
                acc[m][n] = __builtin_amdgcn_mfma_f32_16x16x32_bf16(af[m], bfv[n], acc[m][n], 0, 0, 0);
    }

    // epilogue: out = SCALE * acc
#pragma unroll
    for (int m = 0; m < 2; ++m)
#pragma unroll
        for (int n = 0; n < 2; ++n)
#pragma unroll
            for (int j = 0; j < 4; ++j) {
                int s = s0 + wm * 32 + m * 16 + ((lane >> 4) << 2) + j;
                int o = o0 + wn * 32 + n * 16 + (lane & 15);
                out[((size_t)b * SEQ + s) * OUT_D + o] = SCALE * acc[m][n][j];
            }
}

extern "C" void kernel_launch(void* const* d_in, const int* in_sizes, int n_in,
                              void* d_out, int out_size, void* d_ws, size_t ws_size,
                              hipStream_t stream) {
    const float* graph_rep = (const float*)d_in[0];   // [8,128,4096]
    const float* x         = (const float*)d_in[1];   // [8,2048,4096]
    const float* Wd        = (const float*)d_in[2];   // [128,4096]
    float* out             = (float*)d_out;           // [8,2048,4096]
    unsigned short* down   = (unsigned short*)d_ws;   // [16384,128] bf16 scratch

    k_down<<<M1 / BM1, 512, 0, stream>>>(x, Wd, down);
    k_out<<<BSZ * (SEQ / BM2) * (OUT_D / BN2), 512, 0, stream>>>(down, graph_rep, out);
}

// Round 2
// 233.506 us; speedup vs baseline: 1.0875x; 1.0875x over previous
//
#include <hip/hip_runtime.h>
#include <stdint.h>

#define IN_F   4096
#define R_DIM  128
#define OUT_D  4096
#define BSZ    8
#define SEQ    2048
#define M1     (BSZ * SEQ)   /* 16384 */
#define SCALE  2.0f
#define KSPLIT 4
#define KCHUNK (IN_F / KSPLIT)   /* 1024 */

typedef __attribute__((ext_vector_type(8))) short short8;
typedef __attribute__((ext_vector_type(4))) float f32x4;

static __device__ __forceinline__ unsigned short f32_to_bf16_rne(float f) {
    union { float f; uint32_t u; } v; v.f = f;
    uint32_t u = v.u;
    u += 0x7FFFu + ((u >> 16) & 1u);   // round-to-nearest-even
    return (unsigned short)(u >> 16);
}

static __device__ __forceinline__ float bf16_to_f32(unsigned short h) {
    union { uint32_t u; float f; } v; v.u = ((uint32_t)h) << 16;
    return v.f;
}

static __device__ __forceinline__ void st_bf16x4(unsigned short* p, float4 v) {
    uint2 q;
    q.x = (uint32_t)f32_to_bf16_rne(v.x) | ((uint32_t)f32_to_bf16_rne(v.y) << 16);
    q.y = (uint32_t)f32_to_bf16_rne(v.z) | ((uint32_t)f32_to_bf16_rne(v.w) << 16);
    *(uint2*)p = q;
}

// ---------------- Pass 1 (K-split): part[ks][16384][128] (bf16) = x[:, ks-chunk] @ W_down[:, ks-chunk]^T ----------------
#define BM1 64
#define BK1 64
#define PAD 8

__global__ __launch_bounds__(512) void k_down_split(const float* __restrict__ x,
                                                    const float* __restrict__ Wd,
                                                    unsigned short* __restrict__ part) {
    __shared__ unsigned short As[BM1][BK1 + PAD];      // 64 x 72 bf16
    __shared__ unsigned short Bs[R_DIM][BK1 + PAD];    // 128 x 72 bf16

    const int tid  = threadIdx.x;
    const int lane = tid & 63;
    const int w    = tid >> 6;   // 0..7
    const int wm   = w >> 2;     // 0..1
    const int wn   = w & 3;      // 0..3
    const int mt   = blockIdx.x >> 2;       // 0..255 m-tile
    const int ks   = blockIdx.x & 3;        // 0..3 k-chunk
    const int row0 = mt * BM1;
    const int kbeg = ks * KCHUNK;

    f32x4 acc[2][2];
#pragma unroll
    for (int m = 0; m < 2; ++m)
#pragma unroll
        for (int n = 0; n < 2; ++n)
#pragma unroll
            for (int j = 0; j < 4; ++j) acc[m][n][j] = 0.0f;

    const int arow = tid >> 4;          // 0..31
    const int acol = (tid & 15) << 2;   // 0..60 step 4

    float4 ra[2], rb[4];

    // prologue: load tile 0
    ra[0] = *(const float4*)(x + (size_t)(row0 + arow) * IN_F + kbeg + acol);
    ra[1] = *(const float4*)(x + (size_t)(row0 + arow + 32) * IN_F + kbeg + acol);
#pragma unroll
    for (int i = 0; i < 4; ++i)
        rb[i] = *(const float4*)(Wd + (size_t)(arow + 32 * i) * IN_F + kbeg + acol);
    st_bf16x4(&As[arow][acol], ra[0]);
    st_bf16x4(&As[arow + 32][acol], ra[1]);
#pragma unroll
    for (int i = 0; i < 4; ++i) st_bf16x4(&Bs[arow + 32 * i][acol], rb[i]);
    __syncthreads();

    for (int k0 = kbeg + BK1; k0 <= kbeg + KCHUNK; k0 += BK1) {
        const bool more = (k0 < kbeg + KCHUNK);
        if (more) {
            ra[0] = *(const float4*)(x + (size_t)(row0 + arow) * IN_F + k0 + acol);
            ra[1] = *(const float4*)(x + (size_t)(row0 + arow + 32) * IN_F + k0 + acol);
#pragma unroll
            for (int i = 0; i < 4; ++i)
                rb[i] = *(const float4*)(Wd + (size_t)(arow + 32 * i) * IN_F + k0 + acol);
        }
#pragma unroll
        for (int kk = 0; kk < BK1; kk += 32) {
            short8 af[2], bfv[2];
#pragma unroll
            for (int m = 0; m < 2; ++m)
                af[m] = *(const short8*)&As[wm * 32 + m * 16 + (lane & 15)][kk + (lane >> 4) * 8];
#pragma unroll
            for (int n = 0; n < 2; ++n)
                bfv[n] = *(const short8*)&Bs[wn * 32 + n * 16 + (lane & 15)][kk + (lane >> 4) * 8];
#pragma unroll
            for (int m = 0; m < 2; ++m)
#pragma unroll
                for (int n = 0; n < 2; ++n)
                    acc[m][n] = __builtin_amdgcn_mfma_f32_16x16x32_bf16(af[m], bfv[n], acc[m][n], 0, 0, 0);
        }
        __syncthreads();
        if (more) {
            st_bf16x4(&As[arow][acol], ra[0]);
            st_bf16x4(&As[arow + 32][acol], ra[1]);
#pragma unroll
            for (int i = 0; i < 4; ++i) st_bf16x4(&Bs[arow + 32 * i][acol], rb[i]);
            __syncthreads();
        }
    }

    unsigned short* dst = part + (size_t)ks * M1 * R_DIM;
#pragma unroll
    for (int m = 0; m < 2; ++m)
#pragma unroll
        for (int n = 0; n < 2; ++n)
#pragma unroll
            for (int j = 0; j < 4; ++j) {
                int r = row0 + wm * 32 + m * 16 + ((lane >> 4) << 2) + j;
                int c = wn * 32 + n * 16 + (lane & 15);
                dst[(size_t)r * R_DIM + c] = f32_to_bf16_rne(acc[m][n][j]);
            }
}

// ---------------- Reduce: down = sum_ks part[ks] (bf16) ----------------
__global__ __launch_bounds__(512) void k_reduce(const unsigned short* __restrict__ part,
                                                unsigned short* __restrict__ down) {
    const size_t chunk = (size_t)blockIdx.x * 512 + threadIdx.x;   // 8 elems per chunk
    const size_t off = chunk * 8;
    if (off >= (size_t)M1 * R_DIM) return;
    uint4 p0 = *(const uint4*)(part + off);
    uint4 p1 = *(const uint4*)(part + (size_t)1 * M1 * R_DIM + off);
    uint4 p2 = *(const uint4*)(part + (size_t)2 * M1 * R_DIM + off);
    uint4 p3 = *(const uint4*)(part + (size_t)3 * M1 * R_DIM + off);
    uint4 r;
    const uint32_t* a = (const uint32_t*)&p0;
    const uint32_t* b = (const uint32_t*)&p1;
    const uint32_t* c = (const uint32_t*)&p2;
    const uint32_t* d = (const uint32_t*)&p3;
    uint32_t* o = (uint32_t*)&r;
#pragma unroll
    for (int i = 0; i < 4; ++i) {
        float lo = bf16_to_f32((unsigned short)(a[i] & 0xFFFF)) + bf16_to_f32((unsigned short)(b[i] & 0xFFFF))
                 + bf16_to_f32((unsigned short)(c[i] & 0xFFFF)) + bf16_to_f32((unsigned short)(d[i] & 0xFFFF));
        float hi = bf16_to_f32((unsigned short)(a[i] >> 16)) + bf16_to_f32((unsigned short)(b[i] >> 16))
                 + bf16_to_f32((unsigned short)(c[i] >> 16)) + bf16_to_f32((unsigned short)(d[i] >> 16));
        o[i] = (uint32_t)f32_to_bf16_rne(lo) | ((uint32_t)f32_to_bf16_rne(hi) << 16);
    }
    *(uint4*)(down + off) = r;
}

// ---------------- Fallback pass 1 (no split) ----------------
__global__ __launch_bounds__(512) void k_down(const float* __restrict__ x,
                                              const float* __restrict__ Wd,
                                              unsigned short* __restrict__ down) {
    __shared__ unsigned short As[BM1][BK1 + PAD];
    __shared__ unsigned short Bs[R_DIM][BK1 + PAD];

    const int tid  = threadIdx.x;
    const int lane = tid & 63;
    const int w    = tid >> 6;
    const int wm   = w >> 2;
    const int wn   = w & 3;
    const int row0 = blockIdx.x * BM1;

    f32x4 acc[2][2];
#pragma unroll
    for (int m = 0; m < 2; ++m)
#pragma unroll
        for (int n = 0; n < 2; ++n)
#pragma unroll
            for (int j = 0; j < 4; ++j) acc[m][n][j] = 0.0f;

    const int arow = tid >> 4;
    const int acol = (tid & 15) << 2;
    float4 ra[2], rb[4];

    ra[0] = *(const float4*)(x + (size_t)(row0 + arow) * IN_F + acol);
    ra[1] = *(const float4*)(x + (size_t)(row0 + arow + 32) * IN_F + acol);
#pragma unroll
    for (int i = 0; i < 4; ++i)
        rb[i] = *(const float4*)(Wd + (size_t)(arow + 32 * i) * IN_F + acol);
    st_bf16x4(&As[arow][acol], ra[0]);
    st_bf16x4(&As[arow + 32][acol], ra[1]);
#pragma unroll
    for (int i = 0; i < 4; ++i) st_bf16x4(&Bs[arow + 32 * i][acol], rb[i]);
    __syncthreads();

    for (int k0 = BK1; k0 <= IN_F; k0 += BK1) {
        const bool more = (k0 < IN_F);
        if (more) {
            ra[0] = *(const float4*)(x + (size_t)(row0 + arow) * IN_F + k0 + acol);
            ra[1] = *(const float4*)(x + (size_t)(row0 + arow + 32) * IN_F + k0 + acol);
#pragma unroll
            for (int i = 0; i < 4; ++i)
                rb[i] = *(const float4*)(Wd + (size_t)(arow + 32 * i) * IN_F + k0 + acol);
        }
#pragma unroll
        for (int kk = 0; kk < BK1; kk += 32) {
            short8 af[2], bfv[2];
#pragma unroll
            for (int m = 0; m < 2; ++m)
                af[m] = *(const short8*)&As[wm * 32 + m * 16 + (lane & 15)][kk + (lane >> 4) * 8];
#pragma unroll
            for (int n = 0; n < 2; ++n)
                bfv[n] = *(const short8*)&Bs[wn * 32 + n * 16 + (lane & 15)][kk + (lane >> 4) * 8];
#pragma unroll
            for (int m = 0; m < 2; ++m)
#pragma unroll
                for (int n = 0; n < 2; ++n)
                    acc[m][n] = __builtin_amdgcn_mfma_f32_16x16x32_bf16(af[m], bfv[n], acc[m][n], 0, 0, 0);
        }
        __syncthreads();
        if (more) {
            st_bf16x4(&As[arow][acol], ra[0]);
            st_bf16x4(&As[arow + 32][acol], ra[1]);
#pragma unroll
            for (int i = 0; i < 4; ++i) st_bf16x4(&Bs[arow + 32 * i][acol], rb[i]);
            __syncthreads();
        }
    }

#pragma unroll
    for (int m = 0; m < 2; ++m)
#pragma unroll
        for (int n = 0; n < 2; ++n)
#pragma unroll
            for (int j = 0; j < 4; ++j) {
                int r = row0 + wm * 32 + m * 16 + ((lane >> 4) << 2) + j;
                int c = wn * 32 + n * 16 + (lane & 15);
                down[(size_t)r * R_DIM + c] = f32_to_bf16_rne(acc[m][n][j]);
            }
}

// ---------------- Pass 2: out[b][2048][4096] = down[b] @ graph_rep[b] * SCALE ----------------
#define BM2 64
#define BN2 128
#define KPAD (R_DIM + 8)   /* 136 */

__global__ __launch_bounds__(512) void k_out(const unsigned short* __restrict__ down,
                                             const float* __restrict__ g,
                                             float* __restrict__ out) {
    __shared__ unsigned short As[BM2][KPAD];
    __shared__ unsigned short Bs[BN2][KPAD];

    const int tid  = threadIdx.x;
    const int lane = tid & 63;
    const int w    = tid >> 6;
    const int wm   = w >> 2;
    const int wn   = w & 3;
    const int blk  = blockIdx.x;
    const int o_t  = blk & 31;
    const int s_t  = (blk >> 5) & 31;
    const int b    = blk >> 10;
    const int s0   = s_t * BM2;
    const int o0   = o_t * BN2;

    {
        const int rr = tid >> 4;
        const int c8 = (tid & 15) << 3;
        *(uint4*)&As[rr][c8]      = *(const uint4*)(down + ((size_t)(b * SEQ + s0 + rr) * R_DIM) + c8);
        *(uint4*)&As[rr + 32][c8] = *(const uint4*)(down + ((size_t)(b * SEQ + s0 + rr + 32) * R_DIM) + c8);
    }
    {
        const int kbase = tid >> 5;
        const int c4 = (tid & 31) << 2;
#pragma unroll
        for (int i = 0; i < 8; ++i) {
            int k = kbase + 16 * i;
            float4 v = *(const float4*)(g + ((size_t)b * R_DIM + k) * OUT_D + o0 + c4);
            Bs[c4 + 0][k] = f32_to_bf16_rne(v.x);
            Bs[c4 + 1][k] = f32_to_bf16_rne(v.y);
            Bs[c4 + 2][k] = f32_to_bf16_rne(v.z);
            Bs[c4 + 3][k] = f32_to_bf16_rne(v.w);
        }
    }
    __syncthreads();

    f32x4 acc[2][2];
#pragma unroll
    for (int m = 0; m < 2; ++m)
#pragma unroll
        for (int n = 0; n < 2; ++n)
#pragma unroll
            for (int j = 0; j < 4; ++j) acc[m][n][j] = 0.0f;

#pragma unroll
    for (int kk = 0; kk < R_DIM; kk += 32) {
        short8 af[2], bfv[2];
#pragma unroll
        for (int m = 0; m < 2; ++m)
            af[m] = *(const short8*)&As[wm * 32 + m * 16 + (lane & 15)][kk + (lane >> 4) * 8];
#pragma unroll
        for (int n = 0; n < 2; ++n)
            bfv[n] = *(const short8*)&Bs[wn * 32 + n * 16 + (lane & 15)][kk + (lane >> 4) * 8];
#pragma unroll
        for (int m = 0; m < 2; ++m)
#pragma unroll
            for (int n = 0; n < 2; ++n)
                acc[m][n] = __builtin_amdgcn_mfma_f32_16x16x32_bf16(af[m], bfv[n], acc[m][n], 0, 0, 0);
    }

#pragma unroll
    for (int m = 0; m < 2; ++m)
#pragma unroll
        for (int n = 0; n < 2; ++n)
#pragma unroll
            for (int j = 0; j < 4; ++j) {
                int s = s0 + wm * 32 + m * 16 + ((lane >> 4) << 2) + j;
                int o = o0 + wn * 32 + n * 16 + (lane & 15);
                out[((size_t)b * SEQ + s) * OUT_D + o] = SCALE * acc[m][n][j];
            }
}

extern "C" void kernel_launch(void* const* d_in, const int* in_sizes, int n_in,
                              void* d_out, int out_size, void* d_ws, size_t ws_size,
                              hipStream_t stream) {
    const float* graph_rep = (const float*)d_in[0];   // [8,128,4096]
    const float* x         = (const float*)d_in[1];   // [8,2048,4096]
    const float* Wd        = (const float*)d_in[2];   // [128,4096]
    float* out             = (float*)d_out;           // [8,2048,4096]

    const size_t down_elems = (size_t)M1 * R_DIM;                  // 2M bf16 = 4 MB
    const size_t need_split = (KSPLIT + 1) * down_elems * sizeof(unsigned short);  // 20 MB

    if (ws_size >= need_split) {
        unsigned short* part = (unsigned short*)d_ws;                  // [4][16384][128] bf16
        unsigned short* down = part + (size_t)KSPLIT * down_elems;     // [16384][128] bf16
        k_down_split<<<(M1 / BM1) * KSPLIT, 512, 0, stream>>>(x, Wd, part);
        k_reduce<<<(int)((down_elems / 8 + 511) / 512), 512, 0, stream>>>(part, down);
        k_out<<<BSZ * (SEQ / BM2) * (OUT_D / BN2), 512, 0, stream>>>(down, graph_rep, out);
    } else {
        unsigned short* down = (unsigned short*)d_ws;
        k_down<<<M1 / BM1, 512, 0, stream>>>(x, Wd, down);
        k_out<<<BSZ * (SEQ / BM2) * (OUT_D / BN2), 512, 0, stream>>>(down, graph_rep, out);
    }
}

// Round 3
// 177.362 us; speedup vs baseline: 1.4318x; 1.3165x over previous
//
#include <hip/hip_runtime.h>
#include <stdint.h>

#define IN_F   4096
#define R_DIM  128
#define OUT_D  4096
#define BSZ    8
#define SEQ    2048
#define M1     (BSZ * SEQ)   /* 16384 */
#define SCALE  2.0f
#define KSPLIT 4
#define KCHUNK (IN_F / KSPLIT)   /* 1024 */

typedef __attribute__((ext_vector_type(8))) short short8;
typedef __attribute__((ext_vector_type(4))) float f32x4;

// ---- native bf16 conversion (compiler emits v_cvt_pk_bf16_f32) ----
static __device__ __forceinline__ unsigned short bf16_1(float f) {
    union { __bf16 h; unsigned short u; } v; v.h = (__bf16)f; return v.u;
}
static __device__ __forceinline__ uint32_t pack2(float a, float b) {
    union { __bf16 h[2]; uint32_t u; } v;
    v.h[0] = (__bf16)a; v.h[1] = (__bf16)b;
    return v.u;
}
static __device__ __forceinline__ float bf16_to_f32(unsigned short h) {
    union { uint32_t u; float f; } v; v.u = ((uint32_t)h) << 16;
    return v.f;
}
static __device__ __forceinline__ void st_bf16x4(unsigned short* p, float4 v) {
    uint2 q; q.x = pack2(v.x, v.y); q.y = pack2(v.z, v.w);
    *(uint2*)p = q;
}
// 16B-chunk XOR swizzle: bijective 4-bit mix of row index
static __device__ __forceinline__ int swz16(int r) { return ((r >> 2) ^ r) & 15; }

// ---------------- Pass 1 (K-split): part[ks][16384][128] (bf16) ----------------
#define BM1 64
#define BK1 64
#define PAD 8

__global__ __launch_bounds__(512) void k_down_split(const float* __restrict__ x,
                                                    const float* __restrict__ Wd,
                                                    unsigned short* __restrict__ part) {
    __shared__ unsigned short As[BM1][BK1 + PAD];      // 64 x 72 bf16
    __shared__ unsigned short Bs[R_DIM][BK1 + PAD];    // 128 x 72 bf16

    const int tid  = threadIdx.x;
    const int lane = tid & 63;
    const int w    = tid >> 6;
    const int wm   = w >> 2;
    const int wn   = w & 3;
    const int mt   = blockIdx.x >> 2;
    const int ks   = blockIdx.x & 3;
    const int row0 = mt * BM1;
    const int kbeg = ks * KCHUNK;

    f32x4 acc[2][2];
#pragma unroll
    for (int m = 0; m < 2; ++m)
#pragma unroll
        for (int n = 0; n < 2; ++n)
#pragma unroll
            for (int j = 0; j < 4; ++j) acc[m][n][j] = 0.0f;

    const int arow = tid >> 4;
    const int acol = (tid & 15) << 2;

    float4 ra[2], rb[4];

    ra[0] = *(const float4*)(x + (size_t)(row0 + arow) * IN_F + kbeg + acol);
    ra[1] = *(const float4*)(x + (size_t)(row0 + arow + 32) * IN_F + kbeg + acol);
#pragma unroll
    for (int i = 0; i < 4; ++i)
        rb[i] = *(const float4*)(Wd + (size_t)(arow + 32 * i) * IN_F + kbeg + acol);
    st_bf16x4(&As[arow][acol], ra[0]);
    st_bf16x4(&As[arow + 32][acol], ra[1]);
#pragma unroll
    for (int i = 0; i < 4; ++i) st_bf16x4(&Bs[arow + 32 * i][acol], rb[i]);
    __syncthreads();

    for (int k0 = kbeg + BK1; k0 <= kbeg + KCHUNK; k0 += BK1) {
        const bool more = (k0 < kbeg + KCHUNK);
        if (more) {
            ra[0] = *(const float4*)(x + (size_t)(row0 + arow) * IN_F + k0 + acol);
            ra[1] = *(const float4*)(x + (size_t)(row0 + arow + 32) * IN_F + k0 + acol);
#pragma unroll
            for (int i = 0; i < 4; ++i)
                rb[i] = *(const float4*)(Wd + (size_t)(arow + 32 * i) * IN_F + k0 + acol);
        }
#pragma unroll
        for (int kk = 0; kk < BK1; kk += 32) {
            short8 af[2], bfv[2];
#pragma unroll
            for (int m = 0; m < 2; ++m)
                af[m] = *(const short8*)&As[wm * 32 + m * 16 + (lane & 15)][kk + (lane >> 4) * 8];
#pragma unroll
            for (int n = 0; n < 2; ++n)
                bfv[n] = *(const short8*)&Bs[wn * 32 + n * 16 + (lane & 15)][kk + (lane >> 4) * 8];
#pragma unroll
            for (int m = 0; m < 2; ++m)
#pragma unroll
                for (int n = 0; n < 2; ++n)
                    acc[m][n] = __builtin_amdgcn_mfma_f32_16x16x32_bf16(af[m], bfv[n], acc[m][n], 0, 0, 0);
        }
        __syncthreads();
        if (more) {
            st_bf16x4(&As[arow][acol], ra[0]);
            st_bf16x4(&As[arow + 32][acol], ra[1]);
#pragma unroll
            for (int i = 0; i < 4; ++i) st_bf16x4(&Bs[arow + 32 * i][acol], rb[i]);
            __syncthreads();
        }
    }

    unsigned short* dst = part + (size_t)ks * M1 * R_DIM;
#pragma unroll
    for (int m = 0; m < 2; ++m)
#pragma unroll
        for (int n = 0; n < 2; ++n)
#pragma unroll
            for (int j = 0; j < 4; ++j) {
                int r = row0 + wm * 32 + m * 16 + ((lane >> 4) << 2) + j;
                int c = wn * 32 + n * 16 + (lane & 15);
                dst[(size_t)r * R_DIM + c] = bf16_1(acc[m][n][j]);
            }
}

// ---------------- Reduce: down = sum_ks part[ks] (bf16) ----------------
__global__ __launch_bounds__(512) void k_reduce(const unsigned short* __restrict__ part,
                                                unsigned short* __restrict__ down) {
    const size_t chunk = (size_t)blockIdx.x * 512 + threadIdx.x;
    const size_t off = chunk * 8;
    if (off >= (size_t)M1 * R_DIM) return;
    uint4 p0 = *(const uint4*)(part + off);
    uint4 p1 = *(const uint4*)(part + (size_t)1 * M1 * R_DIM + off);
    uint4 p2 = *(const uint4*)(part + (size_t)2 * M1 * R_DIM + off);
    uint4 p3 = *(const uint4*)(part + (size_t)3 * M1 * R_DIM + off);
    uint4 r;
    const uint32_t* a = (const uint32_t*)&p0;
    const uint32_t* b = (const uint32_t*)&p1;
    const uint32_t* c = (const uint32_t*)&p2;
    const uint32_t* d = (const uint32_t*)&p3;
    uint32_t* o = (uint32_t*)&r;
#pragma unroll
    for (int i = 0; i < 4; ++i) {
        float lo = bf16_to_f32((unsigned short)(a[i] & 0xFFFF)) + bf16_to_f32((unsigned short)(b[i] & 0xFFFF))
                 + bf16_to_f32((unsigned short)(c[i] & 0xFFFF)) + bf16_to_f32((unsigned short)(d[i] & 0xFFFF));
        float hi = bf16_to_f32((unsigned short)(a[i] >> 16)) + bf16_to_f32((unsigned short)(b[i] >> 16))
                 + bf16_to_f32((unsigned short)(c[i] >> 16)) + bf16_to_f32((unsigned short)(d[i] >> 16));
        o[i] = pack2(lo, hi);
    }
    *(uint4*)(down + off) = r;
}

// ---------------- Fallback pass 1 (no split) ----------------
__global__ __launch_bounds__(512) void k_down(const float* __restrict__ x,
                                              const float* __restrict__ Wd,
                                              unsigned short* __restrict__ down) {
    __shared__ unsigned short As[BM1][BK1 + PAD];
    __shared__ unsigned short Bs[R_DIM][BK1 + PAD];

    const int tid  = threadIdx.x;
    const int lane = tid & 63;
    const int w    = tid >> 6;
    const int wm   = w >> 2;
    const int wn   = w & 3;
    const int row0 = blockIdx.x * BM1;

    f32x4 acc[2][2];
#pragma unroll
    for (int m = 0; m < 2; ++m)
#pragma unroll
        for (int n = 0; n < 2; ++n)
#pragma unroll
            for (int j = 0; j < 4; ++j) acc[m][n][j] = 0.0f;

    const int arow = tid >> 4;
    const int acol = (tid & 15) << 2;
    float4 ra[2], rb[4];

    ra[0] = *(const float4*)(x + (size_t)(row0 + arow) * IN_F + acol);
    ra[1] = *(const float4*)(x + (size_t)(row0 + arow + 32) * IN_F + acol);
#pragma unroll
    for (int i = 0; i < 4; ++i)
        rb[i] = *(const float4*)(Wd + (size_t)(arow + 32 * i) * IN_F + acol);
    st_bf16x4(&As[arow][acol], ra[0]);
    st_bf16x4(&As[arow + 32][acol], ra[1]);
#pragma unroll
    for (int i = 0; i < 4; ++i) st_bf16x4(&Bs[arow + 32 * i][acol], rb[i]);
    __syncthreads();

    for (int k0 = BK1; k0 <= IN_F; k0 += BK1) {
        const bool more = (k0 < IN_F);
        if (more) {
            ra[0] = *(const float4*)(x + (size_t)(row0 + arow) * IN_F + k0 + acol);
            ra[1] = *(const float4*)(x + (size_t)(row0 + arow + 32) * IN_F + k0 + acol);
#pragma unroll
            for (int i = 0; i < 4; ++i)
                rb[i] = *(const float4*)(Wd + (size_t)(arow + 32 * i) * IN_F + k0 + acol);
        }
#pragma unroll
        for (int kk = 0; kk < BK1; kk += 32) {
            short8 af[2], bfv[2];
#pragma unroll
            for (int m = 0; m < 2; ++m)
                af[m] = *(const short8*)&As[wm * 32 + m * 16 + (lane & 15)][kk + (lane >> 4) * 8];
#pragma unroll
            for (int n = 0; n < 2; ++n)
                bfv[n] = *(const short8*)&Bs[wn * 32 + n * 16 + (lane & 15)][kk + (lane >> 4) * 8];
#pragma unroll
            for (int m = 0; m < 2; ++m)
#pragma unroll
                for (int n = 0; n < 2; ++n)
                    acc[m][n] = __builtin_amdgcn_mfma_f32_16x16x32_bf16(af[m], bfv[n], acc[m][n], 0, 0, 0);
        }
        __syncthreads();
        if (more) {
            st_bf16x4(&As[arow][acol], ra[0]);
            st_bf16x4(&As[arow + 32][acol], ra[1]);
#pragma unroll
            for (int i = 0; i < 4; ++i) st_bf16x4(&Bs[arow + 32 * i][acol], rb[i]);
            __syncthreads();
        }
    }

#pragma unroll
    for (int m = 0; m < 2; ++m)
#pragma unroll
        for (int n = 0; n < 2; ++n)
#pragma unroll
            for (int j = 0; j < 4; ++j) {
                int r = row0 + wm * 32 + m * 16 + ((lane >> 4) << 2) + j;
                int c = wn * 32 + n * 16 + (lane & 15);
                down[(size_t)r * R_DIM + c] = bf16_1(acc[m][n][j]);
            }
}

// ---------------- Pass 2: out[b][2048][4096] = down[b] @ graph_rep[b] * SCALE ----------------
#define BM2 64
#define BN2 128

__global__ __launch_bounds__(512) void k_out(const unsigned short* __restrict__ down,
                                             const float* __restrict__ g,
                                             float* __restrict__ out) {
    __shared__ unsigned short As[BM2 * R_DIM];   // 64 x 128 bf16, 16B-chunk XOR swizzled
    __shared__ unsigned short Bs[BN2 * R_DIM];   // 128 x 128 bf16 (g transposed), swizzled

    const int tid  = threadIdx.x;
    const int lane = tid & 63;
    const int w    = tid >> 6;
    const int wm   = w >> 2;
    const int wn   = w & 3;
    const int blk  = blockIdx.x;
    const int o_t  = blk & 31;
    const int s_t  = (blk >> 5) & 31;
    const int b    = blk >> 10;
    const int s0   = s_t * BM2;
    const int o0   = o_t * BN2;

    // stage A: straight bf16 copy of down rows, swizzled 16B chunks
    {
        const int rr = tid >> 4;          // 0..31
        const int j  = tid & 15;          // 16B chunk (8 bf16)
        const int sl0 = j ^ swz16(rr);
        const int sl1 = j ^ swz16(rr + 32);
        *(uint4*)&As[rr * R_DIM + sl0 * 8] =
            *(const uint4*)(down + ((size_t)(b * SEQ + s0 + rr) * R_DIM) + j * 8);
        *(uint4*)&As[(rr + 32) * R_DIM + sl1 * 8] =
            *(const uint4*)(down + ((size_t)(b * SEQ + s0 + rr + 32) * R_DIM) + j * 8);
    }
    // stage B: 4x4 register micro-transpose, packed b64 writes, swizzled
    {
        const int oq  = tid & 31;    // o-quad 0..31
        const int kq0 = tid >> 5;    // k-quad 0..15
#pragma unroll
        for (int rep = 0; rep < 2; ++rep) {
            const int kq = kq0 + 16 * rep;   // 0..31
            float4 v0 = *(const float4*)(g + ((size_t)b * R_DIM + 4 * kq + 0) * OUT_D + o0 + 4 * oq);
            float4 v1 = *(const float4*)(g + ((size_t)b * R_DIM + 4 * kq + 1) * OUT_D + o0 + 4 * oq);
            float4 v2 = *(const float4*)(g + ((size_t)b * R_DIM + 4 * kq + 2) * OUT_D + o0 + 4 * oq);
            float4 v3 = *(const float4*)(g + ((size_t)b * R_DIM + 4 * kq + 3) * OUT_D + o0 + 4 * oq);
            const float* p0 = (const float*)&v0;
            const float* p1 = (const float*)&v1;
            const float* p2 = (const float*)&v2;
            const float* p3 = (const float*)&v3;
#pragma unroll
            for (int i = 0; i < 4; ++i) {
                const int o = 4 * oq + i;
                uint2 q;
                q.x = pack2(p0[i], p1[i]);   // k = 4kq, 4kq+1
                q.y = pack2(p2[i], p3[i]);   // k = 4kq+2, 4kq+3
                const int slot = (kq >> 1) ^ swz16(o);
                *(uint2*)&Bs[o * R_DIM + slot * 8 + (kq & 1) * 4] = q;
            }
        }
    }
    __syncthreads();

    f32x4 acc[2][2];
#pragma unroll
    for (int m = 0; m < 2; ++m)
#pragma unroll
        for (int n = 0; n < 2; ++n)
#pragma unroll
            for (int j = 0; j < 4; ++j) acc[m][n][j] = 0.0f;

#pragma unroll
    for (int kk = 0; kk < R_DIM; kk += 32) {
        const int cbase = (kk >> 3) + (lane >> 4);   // 16B chunk index of this lane's 8 k's
        short8 af[2], bfv[2];
#pragma unroll
        for (int m = 0; m < 2; ++m) {
            const int r = wm * 32 + m * 16 + (lane & 15);
            af[m] = *(const short8*)&As[r * R_DIM + (cbase ^ swz16(r)) * 8];
        }
#pragma unroll
        for (int n = 0; n < 2; ++n) {
            const int o = wn * 32 + n * 16 + (lane & 15);
            bfv[n] = *(const short8*)&Bs[o * R_DIM + (cbase ^ swz16(o)) * 8];
        }
#pragma unroll
        for (int m = 0; m < 2; ++m)
#pragma unroll
            for (int n = 0; n < 2; ++n)
                acc[m][n] = __builtin_amdgcn_mfma_f32_16x16x32_bf16(af[m], bfv[n], acc[m][n], 0, 0, 0);
    }

#pragma unroll
    for (int m = 0; m < 2; ++m)
#pragma unroll
        for (int n = 0; n < 2; ++n)
#pragma unroll
            for (int j = 0; j < 4; ++j) {
                int s = s0 + wm * 32 + m * 16 + ((lane >> 4) << 2) + j;
                int o = o0 + wn * 32 + n * 16 + (lane & 15);
                out[((size_t)b * SEQ + s) * OUT_D + o] = SCALE * acc[m][n][j];
            }
}

extern "C" void kernel_launch(void* const* d_in, const int* in_sizes, int n_in,
                              void* d_out, int out_size, void* d_ws, size_t ws_size,
                              hipStream_t stream) {
    const float* graph_rep = (const float*)d_in[0];
    const float* x         = (const float*)d_in[1];
    const float* Wd        = (const float*)d_in[2];
    float* out             = (float*)d_out;

    const size_t down_elems = (size_t)M1 * R_DIM;
    const size_t need_split = (KSPLIT + 1) * down_elems * sizeof(unsigned short);

    if (ws_size >= need_split) {
        unsigned short* part = (unsigned short*)d_ws;
        unsigned short* down = part + (size_t)KSPLIT * down_elems;
        k_down_split<<<(M1 / BM1) * KSPLIT, 512, 0, stream>>>(x, Wd, part);
        k_reduce<<<(int)((down_elems / 8 + 511) / 512), 512, 0, stream>>>(part, down);
        k_out<<<BSZ * (SEQ / BM2) * (OUT_D / BN2), 512, 0, stream>>>(down, graph_rep, out);
    } else {
        unsigned short* down = (unsigned short*)d_ws;
        k_down<<<M1 / BM1, 512, 0, stream>>>(x, Wd, down);
        k_out<<<BSZ * (SEQ / BM2) * (OUT_D / BN2), 512, 0, stream>>>(down, graph_rep, out);
    }
}